// Round 1
// baseline (1679.752 us; speedup 1.0000x reference)
//
#include <hip/hip_runtime.h>

#define NN 100000
#define NE 3200000
#define DD 256
#define NT 8192
#define NOUT 10

typedef unsigned short u16;
typedef __attribute__((ext_vector_type(8))) short bf16x8;
typedef __attribute__((ext_vector_type(4))) float f32x4;

__device__ __forceinline__ float bf2f(u16 u) {
    union { unsigned int i; float f; } v; v.i = ((unsigned int)u) << 16; return v.f;
}
__device__ __forceinline__ u16 f2bf(float f) {
    union { float f; unsigned int i; } v; v.f = f;
    unsigned int x = v.i;
    return (u16)((x + 0x7fffu + ((x >> 16) & 1u)) >> 16);
}

// ---- weight convert + transpose: Wt[l][n][k] = bf16(W[l][k][n]) ----
__global__ __launch_bounds__(256) void k_wt(const float* __restrict__ gW,
                                            const float* __restrict__ lW,
                                            u16* __restrict__ Wt) {
    int idx = blockIdx.x * 256 + threadIdx.x;      // < 6*65536
    int l = idx >> 16;
    int nk = idx & 65535;
    int n = nk >> 8, k = nk & 255;
    float v = (l < 4) ? gW[l * 65536 + k * 256 + n]
                      : lW[(l - 4) * 65536 + k * 256 + n];
    Wt[idx] = f2bf(v);
}

// ---- embedding gather -> bf16 x ----
__global__ __launch_bounds__(256) void k_embed(const int* __restrict__ tokens,
                                               const float* __restrict__ emb,
                                               u16* __restrict__ x) {
    int idx = blockIdx.x * 256 + threadIdx.x;      // handles 2 elems
    int n = idx >> 7;
    int d2 = (idx & 127) * 2;
    int t = tokens[n];
    float2 v = *(const float2*)(emb + t * 256 + d2);
    ushort2 o;
    o.x = f2bf(v.x);
    o.y = f2bf(v.y);
    *(ushort2*)(x + n * 256 + d2) = o;
}

__global__ __launch_bounds__(256) void k_zero(int* __restrict__ p, int n) {
    int i = blockIdx.x * 256 + threadIdx.x;
    if (i < n) p[i] = 0;
}

__global__ __launch_bounds__(256) void k_count(const int* __restrict__ dst,
                                               int* __restrict__ degE) {
    int e = blockIdx.x * 256 + threadIdx.x;
    if (e < NE) atomicAdd(&degE[dst[e]], 1);
}

// ---- scan part A: per-block exclusive scan + block sums + dinv ----
__global__ __launch_bounds__(256) void k_scanA(const int* __restrict__ degE,
                                               int* __restrict__ csr_off,
                                               int* __restrict__ blockSums,
                                               float* __restrict__ dinv) {
    __shared__ int s[256];
    int t = threadIdx.x;
    int idx = blockIdx.x * 256 + t;
    int v = (idx < NN) ? degE[idx] : 0;
    if (idx < NN) dinv[idx] = rsqrtf((float)(v + 1));   // deg includes self loop
    s[t] = v;
    __syncthreads();
    for (int o = 1; o < 256; o <<= 1) {
        int add = (t >= o) ? s[t - o] : 0;
        __syncthreads();
        s[t] += add;
        __syncthreads();
    }
    if (idx < NN) csr_off[idx] = s[t] - v;   // block-local exclusive
    if (t == 255) blockSums[blockIdx.x] = s[255];
}

__global__ __launch_bounds__(512) void k_scanB(int* __restrict__ blockSums) {
    __shared__ int s[512];
    int t = threadIdx.x;
    int v = (t < 391) ? blockSums[t] : 0;
    s[t] = v;
    __syncthreads();
    for (int o = 1; o < 512; o <<= 1) {
        int add = (t >= o) ? s[t - o] : 0;
        __syncthreads();
        s[t] += add;
        __syncthreads();
    }
    if (t < 391) blockSums[t] = s[t] - v;    // exclusive
}

__global__ __launch_bounds__(256) void k_scanC(int* __restrict__ csr_off,
                                               const int* __restrict__ blockSums,
                                               int* __restrict__ cur) {
    int idx = blockIdx.x * 256 + threadIdx.x;
    if (idx < NN) {
        int o = csr_off[idx] + blockSums[blockIdx.x];
        csr_off[idx] = o;
        cur[idx] = o;
    }
    if (idx == 0) csr_off[NN] = NE;
}

__global__ __launch_bounds__(256) void k_scatter(const int* __restrict__ src,
                                                 const int* __restrict__ dst,
                                                 int* __restrict__ cur,
                                                 const float* __restrict__ dinv,
                                                 int* __restrict__ csr_src,
                                                 float* __restrict__ csr_w) {
    int e = blockIdx.x * 256 + threadIdx.x;
    if (e >= NE) return;
    int s_ = src[e], d_ = dst[e];
    int pos = atomicAdd(&cur[d_], 1);
    csr_src[pos] = s_;
    csr_w[pos] = dinv[s_] * dinv[d_];
}

// ---- bf16 MFMA GEMM: C[M,256] = A[M,256] @ Bt^T (Bt is [256 n][256 k]) ----
__global__ __launch_bounds__(256) void k_gemm(const u16* __restrict__ A,
                                              const u16* __restrict__ Bt,
                                              u16* __restrict__ C, int M) {
    __shared__ u16 As[128 * 32];
    __shared__ u16 Bs[128 * 32];
    const int tid = threadIdx.x;
    const int wave = tid >> 6, lane = tid & 63;
    const int wm = wave >> 1, wn = wave & 1;
    const int rowBase = blockIdx.x * 128;
    const int colBase = blockIdx.y * 128;
    const int quad = lane >> 4, l16 = lane & 15;

    f32x4 acc[4][4] = {};

    for (int k0 = 0; k0 < 256; k0 += 32) {
        for (int c = tid; c < 512; c += 256) {
            int r = c >> 2, kc = c & 3;
            int grow = rowBase + r;
            if (grow >= M) grow = M - 1;
            uint4 v = *(const uint4*)(A + grow * 256 + k0 + kc * 8);
            int p = kc ^ (r & 3);
            *(uint4*)(As + r * 32 + p * 8) = v;
        }
        for (int c = tid; c < 512; c += 256) {
            int r = c >> 2, kc = c & 3;
            uint4 v = *(const uint4*)(Bt + (colBase + r) * 256 + k0 + kc * 8);
            int p = kc ^ (r & 3);
            *(uint4*)(Bs + r * 32 + p * 8) = v;
        }
        __syncthreads();
        bf16x8 a_frag[4], b_frag[4];
        for (int i = 0; i < 4; i++) {
            int r = wm * 64 + i * 16 + l16;
            int p = quad ^ (r & 3);
            a_frag[i] = *(const bf16x8*)(As + r * 32 + p * 8);
        }
        for (int j = 0; j < 4; j++) {
            int r = wn * 64 + j * 16 + l16;
            int p = quad ^ (r & 3);
            b_frag[j] = *(const bf16x8*)(Bs + r * 32 + p * 8);
        }
        for (int i = 0; i < 4; i++)
            for (int j = 0; j < 4; j++)
                acc[i][j] = __builtin_amdgcn_mfma_f32_16x16x32_bf16(
                    a_frag[i], b_frag[j], acc[i][j], 0, 0, 0);
        __syncthreads();
    }
    for (int i = 0; i < 4; i++)
        for (int j = 0; j < 4; j++) {
            int col = colBase + wn * 64 + j * 16 + l16;
            for (int r = 0; r < 4; r++) {
                int row = rowBase + wm * 64 + i * 16 + quad * 4 + r;
                if (row < M) C[row * 256 + col] = f2bf(acc[i][j][r]);
            }
        }
}

// ---- fused aggregate (self loop + CSR edges) + bias + LN + ReLU ----
__global__ __launch_bounds__(256) void k_aggr(const u16* __restrict__ h,
                                              const int* __restrict__ csr_off,
                                              const int* __restrict__ csr_src,
                                              const float* __restrict__ csr_w,
                                              const float* __restrict__ dinv,
                                              const float* __restrict__ bias,
                                              const float* __restrict__ gamma,
                                              const float* __restrict__ beta,
                                              u16* __restrict__ xo) {
    int wave = threadIdx.x >> 6, lane = threadIdx.x & 63;
    int node = blockIdx.x * 4 + wave;
    float dn = dinv[node];
    int base = node * 256 + lane * 4;
    ushort4 hv = *(const ushort4*)(h + base);
    float w0 = dn * dn;
    float a0 = w0 * bf2f(hv.x), a1 = w0 * bf2f(hv.y);
    float a2 = w0 * bf2f(hv.z), a3 = w0 * bf2f(hv.w);
    int beg = csr_off[node], end = csr_off[node + 1];
    int e = beg;
    for (; e + 4 <= end; e += 4) {
        int s0 = csr_src[e + 0], s1 = csr_src[e + 1];
        int s2 = csr_src[e + 2], s3 = csr_src[e + 3];
        float we0 = csr_w[e + 0], we1 = csr_w[e + 1];
        float we2 = csr_w[e + 2], we3 = csr_w[e + 3];
        ushort4 v0 = *(const ushort4*)(h + s0 * 256 + lane * 4);
        ushort4 v1 = *(const ushort4*)(h + s1 * 256 + lane * 4);
        ushort4 v2 = *(const ushort4*)(h + s2 * 256 + lane * 4);
        ushort4 v3 = *(const ushort4*)(h + s3 * 256 + lane * 4);
        a0 = fmaf(we0, bf2f(v0.x), a0); a1 = fmaf(we0, bf2f(v0.y), a1);
        a2 = fmaf(we0, bf2f(v0.z), a2); a3 = fmaf(we0, bf2f(v0.w), a3);
        a0 = fmaf(we1, bf2f(v1.x), a0); a1 = fmaf(we1, bf2f(v1.y), a1);
        a2 = fmaf(we1, bf2f(v1.z), a2); a3 = fmaf(we1, bf2f(v1.w), a3);
        a0 = fmaf(we2, bf2f(v2.x), a0); a1 = fmaf(we2, bf2f(v2.y), a1);
        a2 = fmaf(we2, bf2f(v2.z), a2); a3 = fmaf(we2, bf2f(v2.w), a3);
        a0 = fmaf(we3, bf2f(v3.x), a0); a1 = fmaf(we3, bf2f(v3.y), a1);
        a2 = fmaf(we3, bf2f(v3.z), a2); a3 = fmaf(we3, bf2f(v3.w), a3);
    }
    for (; e < end; ++e) {
        int s = csr_src[e];
        float w = csr_w[e];
        ushort4 v = *(const ushort4*)(h + s * 256 + lane * 4);
        a0 = fmaf(w, bf2f(v.x), a0); a1 = fmaf(w, bf2f(v.y), a1);
        a2 = fmaf(w, bf2f(v.z), a2); a3 = fmaf(w, bf2f(v.w), a3);
    }
    float4 bv = *(const float4*)(bias + lane * 4);
    a0 += bv.x; a1 += bv.y; a2 += bv.z; a3 += bv.w;
    float s1 = a0 + a1 + a2 + a3;
    float s2 = a0 * a0 + a1 * a1 + a2 * a2 + a3 * a3;
    for (int o = 32; o >= 1; o >>= 1) {
        s1 += __shfl_xor(s1, o, 64);
        s2 += __shfl_xor(s2, o, 64);
    }
    float mean = s1 * (1.0f / 256.0f);
    float var = s2 * (1.0f / 256.0f) - mean * mean;
    float rstd = rsqrtf(var + 1e-5f);
    float4 gv = *(const float4*)(gamma + lane * 4);
    float4 be = *(const float4*)(beta + lane * 4);
    float y0 = fmaxf((a0 - mean) * rstd * gv.x + be.x, 0.0f);
    float y1 = fmaxf((a1 - mean) * rstd * gv.y + be.y, 0.0f);
    float y2 = fmaxf((a2 - mean) * rstd * gv.z + be.z, 0.0f);
    float y3 = fmaxf((a3 - mean) * rstd * gv.w + be.w, 0.0f);
    ushort4 o4;
    o4.x = f2bf(y0); o4.y = f2bf(y1); o4.z = f2bf(y2); o4.w = f2bf(y3);
    *(ushort4*)(xo + base) = o4;
}

__global__ __launch_bounds__(256) void k_gather(const u16* __restrict__ x,
                                                const int* __restrict__ tgt,
                                                u16* __restrict__ xt) {
    int wave = threadIdx.x >> 6, lane = threadIdx.x & 63;
    int row = blockIdx.x * 4 + wave;
    int t = tgt[row];
    *(ushort4*)(xt + row * 256 + lane * 4) =
        *(const ushort4*)(x + t * 256 + lane * 4);
}

__global__ __launch_bounds__(256) void k_lnrelu(const u16* __restrict__ h,
                                                const float* __restrict__ bias,
                                                const float* __restrict__ gamma,
                                                const float* __restrict__ beta,
                                                u16* __restrict__ xo) {
    int wave = threadIdx.x >> 6, lane = threadIdx.x & 63;
    int row = blockIdx.x * 4 + wave;
    int base = row * 256 + lane * 4;
    ushort4 hv = *(const ushort4*)(h + base);
    float4 bv = *(const float4*)(bias + lane * 4);
    float a0 = bf2f(hv.x) + bv.x, a1 = bf2f(hv.y) + bv.y;
    float a2 = bf2f(hv.z) + bv.z, a3 = bf2f(hv.w) + bv.w;
    float s1 = a0 + a1 + a2 + a3;
    float s2 = a0 * a0 + a1 * a1 + a2 * a2 + a3 * a3;
    for (int o = 32; o >= 1; o >>= 1) {
        s1 += __shfl_xor(s1, o, 64);
        s2 += __shfl_xor(s2, o, 64);
    }
    float mean = s1 * (1.0f / 256.0f);
    float var = s2 * (1.0f / 256.0f) - mean * mean;
    float rstd = rsqrtf(var + 1e-5f);
    float4 gv = *(const float4*)(gamma + lane * 4);
    float4 be = *(const float4*)(beta + lane * 4);
    float y0 = fmaxf((a0 - mean) * rstd * gv.x + be.x, 0.0f);
    float y1 = fmaxf((a1 - mean) * rstd * gv.y + be.y, 0.0f);
    float y2 = fmaxf((a2 - mean) * rstd * gv.z + be.z, 0.0f);
    float y3 = fmaxf((a3 - mean) * rstd * gv.w + be.w, 0.0f);
    ushort4 o4;
    o4.x = f2bf(y0); o4.y = f2bf(y1); o4.z = f2bf(y2); o4.w = f2bf(y3);
    *(ushort4*)(xo + base) = o4;
}

__global__ __launch_bounds__(256) void k_out(const u16* __restrict__ x,
                                             const float* __restrict__ W,
                                             const float* __restrict__ b,
                                             float* __restrict__ out) {
    int wave = threadIdx.x >> 6, lane = threadIdx.x & 63;
    int row = blockIdx.x * 4 + wave;
    ushort4 v = *(const ushort4*)(x + row * 256 + lane * 4);
    float x0 = bf2f(v.x), x1 = bf2f(v.y), x2 = bf2f(v.z), x3 = bf2f(v.w);
    int d = lane * 4;
    for (int o = 0; o < NOUT; o++) {
        float p = x0 * W[(d + 0) * NOUT + o] + x1 * W[(d + 1) * NOUT + o] +
                  x2 * W[(d + 2) * NOUT + o] + x3 * W[(d + 3) * NOUT + o];
        for (int off = 32; off >= 1; off >>= 1) p += __shfl_xor(p, off, 64);
        if (lane == 0) out[row * NOUT + o] = p + b[o];
    }
}

extern "C" void kernel_launch(void* const* d_in, const int* in_sizes, int n_in,
                              void* d_out, int out_size, void* d_ws, size_t ws_size,
                              hipStream_t stream) {
    (void)in_sizes; (void)n_in; (void)out_size; (void)ws_size;
    const int* tokens = (const int*)d_in[0];
    const int* edges = (const int*)d_in[1];
    const int* tgt = (const int*)d_in[2];
    const float* emb = (const float*)d_in[3];
    const float* gnn_W = (const float*)d_in[4];
    const float* gnn_b = (const float*)d_in[5];
    const float* gnn_g = (const float*)d_in[6];
    const float* gnn_be = (const float*)d_in[7];
    const float* lin_W = (const float*)d_in[8];
    const float* lin_b = (const float*)d_in[9];
    const float* lin_g = (const float*)d_in[10];
    const float* lin_be = (const float*)d_in[11];
    const float* out_W = (const float*)d_in[12];
    const float* out_b = (const float*)d_in[13];
    float* out = (float*)d_out;

    char* ws = (char*)d_ws;
    u16* x = (u16*)ws;           ws += (size_t)NN * 256 * 2;
    u16* h = (u16*)ws;           ws += (size_t)NN * 256 * 2;
    int* csr_src = (int*)ws;     ws += (size_t)NE * 4;
    float* csr_w = (float*)ws;   ws += (size_t)NE * 4;
    int* degE = (int*)ws;        ws += (size_t)NN * 4;
    float* dinv = (float*)ws;    ws += (size_t)NN * 4;
    int* csr_off = (int*)ws;     ws += (size_t)(NN + 4) * 4;
    int* cur = (int*)ws;         ws += (size_t)NN * 4;
    int* blockSums = (int*)ws;   ws += 512 * 4;
    u16* Wt = (u16*)ws;          ws += (size_t)6 * 65536 * 2;
    u16* xt = (u16*)ws;          ws += (size_t)NT * 256 * 2;
    u16* ht = (u16*)ws;          ws += (size_t)NT * 256 * 2;

    const int* e_src = edges;
    const int* e_dst = edges + NE;

    k_wt<<<1536, 256, 0, stream>>>(gnn_W, lin_W, Wt);
    k_embed<<<50000, 256, 0, stream>>>(tokens, emb, x);
    k_zero<<<391, 256, 0, stream>>>(degE, NN);
    k_count<<<12500, 256, 0, stream>>>(e_dst, degE);
    k_scanA<<<391, 256, 0, stream>>>(degE, csr_off, blockSums, dinv);
    k_scanB<<<1, 512, 0, stream>>>(blockSums);
    k_scanC<<<391, 256, 0, stream>>>(csr_off, blockSums, cur);
    k_scatter<<<12500, 256, 0, stream>>>(e_src, e_dst, cur, dinv, csr_src, csr_w);

    for (int l = 0; l < 4; l++) {
        k_gemm<<<dim3(782, 2), 256, 0, stream>>>(x, Wt + l * 65536, h, NN);
        k_aggr<<<25000, 256, 0, stream>>>(h, csr_off, csr_src, csr_w, dinv,
                                          gnn_b + l * 256, gnn_g + l * 256,
                                          gnn_be + l * 256, x);
    }
    k_gather<<<2048, 256, 0, stream>>>(x, tgt, xt);
    for (int l = 0; l < 2; l++) {
        k_gemm<<<dim3(64, 2), 256, 0, stream>>>(xt, Wt + (4 + l) * 65536, ht, NT);
        k_lnrelu<<<2048, 256, 0, stream>>>(ht, lin_b + l * 256, lin_g + l * 256,
                                           lin_be + l * 256, xt);
    }
    k_out<<<2048, 256, 0, stream>>>(xt, out_W, out_b, out);
}